// Round 1
// 146.005 us; speedup vs baseline: 1.0172x; 1.0172x over previous
//
#include <hip/hip_runtime.h>
#include <math.h>

#define MAX_SLOTS 64
#define L 4096

// ws layout (bytes)
#define OFF_CNT   0
#define OFF_LIST  64          // 64 ints
#define OFF_FSUB  512         // 2*64*66*66*4 = 2230272 (zero-padded border)
#define OFF_K5    2230784     // 2*64*64*28*4 = 1835008  [b][c][slot][28]
#define OFF_SF    4065792     // 2*64*4096*4 = 2097152   [b][slot][P]

// Deterministic mask->list (ascending q). Needs full 256-thread block.
__device__ __forceinline__ void build_list(const int* __restrict__ mask,
                                           unsigned int* flagw, int* llist,
                                           int* lcnt) {
    int tid = threadIdx.x;
    for (int w = tid; w < 128; w += 256) flagw[w] = 0u;
    __syncthreads();
    int q0 = tid * 16;
    unsigned int mybits = 0u;
    for (int k = 0; k < 16; ++k) {
        int q = q0 + k;
        int qi = q >> 6, qj = q & 63;
        bool allz = true;
        for (int dy = -1; dy <= 1; ++dy)
            for (int dx = -1; dx <= 1; ++dx) {
                int y = qi + dy, x = qj + dx;
                if (y >= 0 && y < 64 && x >= 0 && x < 64)
                    allz = allz && (mask[y * 64 + x] == 0);
            }
        if (allz) mybits |= (1u << k);
    }
    if (mybits) atomicOr(&flagw[q0 >> 5], mybits << (q0 & 31));
    __syncthreads();
    if (tid < 64) {
        unsigned int w0 = flagw[2 * tid], w1 = flagw[2 * tid + 1];
        int own = __popc(w0) + __popc(w1);
        int inc = own;
        for (int o = 1; o < 64; o <<= 1) {
            int v = __shfl_up(inc, o);
            if (tid >= o) inc += v;
        }
        int pos = inc - own;
        for (int k = 0; k < 32; ++k)
            if (w0 & (1u << k)) { if (pos < MAX_SLOTS) llist[pos] = tid * 64 + k; ++pos; }
        for (int k = 0; k < 32; ++k)
            if (w1 & (1u << k)) { if (pos < MAX_SLOTS) llist[pos] = tid * 64 + 32 + k; ++pos; }
        if (tid == 63) *lcnt = (inc < MAX_SLOTS) ? inc : MAX_SLOTS;
    }
    __syncthreads();
}

// ---- D0: prep blocks (K5 from in-direct reads) + data blocks
//          (subsample+pad, sf zero, passthrough, canonical list) ----
__global__ __launch_bounds__(256) void k_front(const float* __restrict__ in,
                                               const int* __restrict__ mask,
                                               int* __restrict__ cnt,
                                               int* __restrict__ list,
                                               float* __restrict__ fsub,
                                               float* __restrict__ K5,
                                               float* __restrict__ sf,
                                               float* __restrict__ out) {
    __shared__ float patch9[5184];
    __shared__ unsigned int flagw[128];
    __shared__ int llist[MAX_SLOTS];
    __shared__ int lcnt;
    __shared__ int iflags[16];
    int tid = threadIdx.x;
    int blk = blockIdx.x;

    if (blk < 128) {
        int slot = blk & 63, b = blk >> 6;
        build_list(mask, flagw, llist, &lcnt);
        int nact = lcnt;
        if (blk == 0) {                         // publish canonical list
            if (tid < MAX_SLOTS) list[tid] = llist[tid];
            if (tid == 64) *cnt = nact;
        }
        if (slot >= nact) {
            for (int t = tid; t < 1600; t += 256) {
                int c = t / 25, e = t - c * 25;
                K5[(((size_t)b * 64 + c) * 64 + slot) * 28 + e] = 0.f;
            }
            return;
        }
        if (tid < 16) iflags[tid] = 0;
        __syncthreads();
        int Q = llist[slot];
        const float* inb = in + (size_t)b * 2097152;
        int w = tid >> 6, lane = tid & 63;
        for (int combo = w; combo < 9; combo += 4) {
            int d2 = combo / 3 - 1, d1 = combo % 3 - 1;
            int XQ = ((Q & 63) << 6) + (Q >> 6) + d2;
            if (XQ < 0 || XQ >= L) continue;
            int YQ = ((XQ & 63) << 6) + (XQ >> 6);
            int R = YQ + d1;
            if (R < 0 || R >= L) continue;
            if (lane == 0) iflags[combo] = 1;
            int ri = R >> 6, rj = R & 63;
            float vals[9]; float ss = 0.f;
            #pragma unroll
            for (int k = 0; k < 9; ++k) {
                int t = lane + (k << 6);
                int c = t / 9; int tap = t - c * 9;
                int dy = tap / 3, dx = tap - dy * 3;
                int yy = ri + dy - 1, xx = rj + dx - 1;
                float v = ((unsigned)yy < 64u && (unsigned)xx < 64u)
                          ? inb[((size_t)c << 14) + (yy << 8) + (xx << 1)] : 0.f;
                vals[k] = v; ss += v * v;
            }
            for (int o = 32; o > 0; o >>= 1) ss += __shfl_xor(ss, o);
            float inv = 1.f / fmaxf(sqrtf(ss), 1e-8f);
            float* dst = patch9 + combo * 576;
            #pragma unroll
            for (int k = 0; k < 9; ++k) dst[lane + (k << 6)] = vals[k] * inv;
        }
        __syncthreads();
        for (int t = tid; t < 1600; t += 256) {
            int c = t / 25, e = t - c * 25;
            int oy = e / 5 - 2, ox = e - (e / 5) * 5 - 2;
            float s = 0.f;
            for (int dy = -1; dy <= 1; ++dy) {
                int dd2 = oy - dy; if (dd2 < -1 || dd2 > 1) continue;
                for (int dx = -1; dx <= 1; ++dx) {
                    int dd1 = ox - dx; if (dd1 < -1 || dd1 > 1) continue;
                    int combo = (dd2 + 1) * 3 + (dd1 + 1);
                    if (iflags[combo])
                        s += patch9[combo * 576 + c * 9 + (dy + 1) * 3 + (dx + 1)];
                }
            }
            K5[(((size_t)b * 64 + c) * 64 + slot) * 28 + e] = s;
        }
        return;
    }

    // ===== data blocks =====
    int idx = (blk - 128) * 256 + tid;          // [0, 524288)
    int j = idx & 63;
    int i = (idx >> 6) & 63;
    int c = (idx >> 12) & 63;
    int b = idx >> 18;
    float v = in[(((b * 128 + c) * 128) + 2 * i) * 128 + 2 * j];
    fsub[(size_t)b * 278784 + c * 4356 + (i + 1) * 66 + (j + 1)] = v;
    sf[idx] = 0.f;
    if (idx < 33280) {                          // 260 pad cells x 128 planes
        int plane = idx / 260;
        int r = idx - plane * 260;
        int pb = plane >> 6, pc = plane & 63;
        int row, col;
        if (r < 66) { row = 0; col = r; }
        else if (r < 132) { row = 65; col = r - 66; }
        else { int rr = r - 132; row = (rr >> 1) + 1; col = (rr & 1) ? 65 : 0; }
        fsub[(size_t)pb * 278784 + pc * 4356 + row * 66 + col] = 0.f;
    }
    // passthrough b_full / f_full
    #pragma unroll
    for (int k = 0; k < 4; ++k) {
        int t = idx + k * 524288;               // [0, 2097152)
        int pix = t & 16383;
        int cc = (t >> 14) & 63;
        int bb = t >> 20;
        float pv = in[(size_t)(bb * 128 + cc) * 16384 + pix];
        size_t ob = (size_t)bb * 3145728;
        out[ob + (size_t)cc * 16384 + pix] = pv;
        out[ob + (size_t)(cc + 64) * 16384 + pix] = pv;
    }
}

// ---- D1: blocks 0..495 interior 5x5 conv; blocks 496..1647 border pixels ----
__global__ __launch_bounds__(256) void k_mid2(const int* __restrict__ cnt,
                                              const int* __restrict__ list,
                                              const float* __restrict__ fsub,
                                              const float* __restrict__ K5,
                                              float* __restrict__ sf) {
    __shared__ float smem[840];
    int tid = threadIdx.x;
    int blk = blockIdx.x;
    int nact = min(*cnt, MAX_SLOTS);
    if (nact == 0) return;

    if (blk < 496) {
        // ===== interior 5x5 conv, scalar (s_load) K5 reads =====
        int wid = __builtin_amdgcn_readfirstlane(blk * 4 + (tid >> 6)); // 0..1983
        int j = tid & 63;
        int r   = 1 + (wid % 62);
        int cg2 = (wid / 62) & 15;
        int b   = wid / 992;
        int jc = min(max(j, 1), 62);
        const float* F = fsub + (size_t)b * 278784;
        int base = (r - 1) * 66 + (jc - 1);
        bool active = (j >= 1 && j <= 62);
        int P = (r << 6) + j;
        for (int s0 = 0; s0 < nact; s0 += 16) {
            float acc[16];
            #pragma unroll
            for (int s = 0; s < 16; ++s) acc[s] = 0.f;
            #pragma unroll
            for (int cc = 0; cc < 4; ++cc) {
                int c = cg2 * 4 + cc;
                const float* Fc = F + c * 4356 + base;
                float win[25];
                #pragma unroll
                for (int dy = 0; dy < 5; ++dy)
                    #pragma unroll
                    for (int dx = 0; dx < 5; ++dx)
                        win[dy * 5 + dx] = Fc[dy * 66 + dx];
                const float* kc = K5 + (((size_t)b * 64 + c) * 64 + s0) * 28;
                #pragma unroll
                for (int s = 0; s < 16; ++s) {
                    #pragma unroll
                    for (int k = 0; k < 25; ++k)
                        acc[s] += kc[s * 28 + k] * win[k];
                }
            }
            if (active) {
                int smax = min(16, nact - s0);
                for (int s = 0; s < smax; ++s)
                    atomicAdd(&sf[((size_t)b * 64 + (s0 + s)) * 4096 + P], acc[s]);
            }
        }
        return;
    }

    // ===== border: exact per-combo scores for the 252 edge pixels =====
    int bt = blk - 496;                       // 0..1151
    int combo = bt % 9; int rest = bt / 9;
    int slot = rest & 63, b = rest >> 6;
    if (slot >= nact) return;
    int d2 = combo / 3 - 1, d1 = combo % 3 - 1;
    int Q = list[slot];
    int XQ = ((Q & 63) << 6) + (Q >> 6) + d2;
    if (XQ < 0 || XQ >= L) return;
    int YQ = ((XQ & 63) << 6) + (XQ >> 6);
    int R = YQ + d1;
    if (R < 0 || R >= L) return;
    int ri = R >> 6, rj = R & 63;
    const float* F = fsub + (size_t)b * 278784;
    float* patch = smem;                      // 576
    float* red = smem + 576;                  // 256
    const float* Fp = F + ri * 66 + rj;
    auto ld = [&](int t) -> float {
        int c = t / 9; int tap = t - c * 9;
        int dy = tap / 3, dx = tap - dy * 3;
        return Fp[c * 4356 + dy * 66 + dx];
    };
    float v0 = ld(tid), v1 = ld(tid + 256), v2 = (tid < 64) ? ld(tid + 512) : 0.f;
    red[tid] = v0 * v0 + v1 * v1 + v2 * v2;
    __syncthreads();
    if (tid < 64) {
        float a = red[tid] + red[tid + 64] + red[tid + 128] + red[tid + 192];
        for (int o = 32; o > 0; o >>= 1) a += __shfl_xor(a, o);
        if (tid == 0) smem[832] = 1.f / fmaxf(sqrtf(a), 1e-8f);
    }
    __syncthreads();
    float inv = smem[832];
    patch[tid] = v0 * inv; patch[tid + 256] = v1 * inv;
    if (tid < 64) patch[tid + 512] = v2 * inv;
    __syncthreads();
    if (tid >= 252) return;
    int i, j;
    if (tid < 64)       { i = 0;  j = tid; }
    else if (tid < 128) { i = 63; j = tid - 64; }
    else if (tid < 190) { i = tid - 127; j = 0; }
    else                { i = tid - 189; j = 63; }
    int P = (i << 6) + j;
    int XP = (j << 6) + i + d2;
    if (XP < 0 || XP >= L) return;
    int YP = ((XP & 63) << 6) + (XP >> 6);
    int Z = YP + d1;
    if (Z < 0 || Z >= L) return;
    int pi = Z >> 6, pj = Z & 63;
    const float* Fz = F + pi * 66 + pj;
    float dot = 0.f;
    #pragma unroll 4
    for (int c = 0; c < 64; ++c) {
        const float* Fc = Fz + c * 4356;
        const float* pc = patch + c * 9;
        dot += Fc[0] * pc[0]   + Fc[1] * pc[1]   + Fc[2] * pc[2];
        dot += Fc[66] * pc[3]  + Fc[67] * pc[4]  + Fc[68] * pc[5];
        dot += Fc[132] * pc[6] + Fc[133] * pc[7] + Fc[134] * pc[8];
    }
    atomicAdd(&sf[((size_t)b * 64 + slot) * 4096 + P], dot);
}

// ---- D2: streamed softmax (M, 1/den) + 16-slot-chunked LDS aggregation ----
// LDS: 16*192*4 + 16*128*4 + 2*192*4 = 22016 B  -> 4+ resident blocks/CU
__global__ __launch_bounds__(256) void k_tail2(const float* __restrict__ in,
                                               const int* __restrict__ mask,
                                               const int* __restrict__ cnt,
                                               const int* __restrict__ list,
                                               const float* __restrict__ sf,
                                               float* __restrict__ out) {
    __shared__ float sw16[16 * 192];
    __shared__ float pat16[16 * 128];
    __shared__ float Mv[192];
    __shared__ float Dv[192];
    int tid = threadIdx.x;
    int nact = min(*cnt, MAX_SLOTS);
    int up = blockIdx.x, cg8 = blockIdx.y, b = blockIdx.z;
    int c0 = cg8 * 8;
    const float* inb0 = in + (size_t)b * 2097152 + (size_t)c0 * 16384;
    const float* sfb = sf + (size_t)b * 262144;

    // pass A: per staged pixel, running max + denominator (streamed from sf)
    if (tid < 192) {
        int i = up - 1 + (tid >> 6); int jj = tid & 63;
        float M = 0.f, invden = 0.f;
        if ((unsigned)i < 64u && nact > 0) {
            const float* sp = sfb + (i << 6) + jj;
            for (int s = 0; s < nact; ++s)
                M = fmaxf(M, 10.f * sp[(size_t)s * 4096]);
            float den = (float)(L - nact) * expf(-M);
            for (int s = 0; s < nact; ++s)
                den += expf(10.f * sp[(size_t)s * 4096] - M);
            invden = 1.f / den;
        }
        Mv[tid] = M; Dv[tid] = invden;
    }

    // aggregation thread constants
    int uu = tid >> 7, v = tid & 127;
    int u = up * 2 + uu;
    bool gate = (mask[(u >> 1) * 64 + (v >> 1)] != 0) && (nact > 0);
    int Wp[4]; int tap[4]; bool val[4];
    {
        int pa = (u + 1) & 1, pb_ = (v + 1) & 1;
        int i0 = (u + 1 - pa) >> 1, j0 = (v + 1 - pb_) >> 1;
        #pragma unroll
        for (int di = 0; di < 2; ++di)
            #pragma unroll
            for (int dj = 0; dj < 2; ++dj) {
                int p = di * 2 + dj;
                int ii = i0 - di, jx = j0 - dj;
                int iis = ii - (up - 1);             // 0..2 within staged rows
                val[p] = (jx >= 0 && jx < 64);
                Wp[p] = val[p] ? (iis * 64 + jx) : 0;
                tap[p] = (pa + 2 * di) * 4 + (pb_ + 2 * dj);
            }
    }
    float y[8];
    #pragma unroll
    for (int cc = 0; cc < 8; ++cc) y[cc] = 0.f;

    for (int s0 = 0; s0 < nact; s0 += 16) {
        int ns = min(16, nact - s0);
        __syncthreads();                  // Mv/Dv ready; prev-iter agg done
        for (int t = tid; t < ns * 192; t += 256) {
            int sl = t / 192; int rr = t - sl * 192;
            int i = up - 1 + (rr >> 6); int jj = rr & 63;
            float wv = 0.f;
            if ((unsigned)i < 64u)
                wv = expf(10.f * sfb[(size_t)(s0 + sl) * 4096 + (i << 6) + jj] - Mv[rr]) * Dv[rr];
            sw16[t] = wv;
        }
        for (int t = tid; t < ns * 128; t += 256) {
            int sl = t >> 7; int rr = t & 127;
            int cc = rr >> 4; int e = rr & 15; int aa = e >> 2; int bb = e & 3;
            int q = list[s0 + sl]; int qi = q >> 6, qj = q & 63;
            int row = 2 * qi - 1 + aa, col = 2 * qj - 1 + bb;
            float pv = (row >= 0 && row < 128 && col >= 0 && col < 128)
                       ? inb0[(size_t)cc * 16384 + row * 128 + col] : 0.f;
            pat16[t] = pv;
        }
        __syncthreads();
        if (gate) {
            for (int s = 0; s < ns; ++s) {
                const float* wrow = sw16 + s * 192;
                const float* ps = pat16 + s * 128;
                #pragma unroll
                for (int p = 0; p < 4; ++p) {
                    if (!val[p]) continue;
                    float wv = wrow[Wp[p]];
                    #pragma unroll
                    for (int cc = 0; cc < 8; ++cc)
                        y[cc] += wv * ps[cc * 16 + tap[p]];
                }
            }
        }
    }
    if (gate) {
        #pragma unroll
        for (int cc = 0; cc < 8; ++cc) y[cc] *= 0.25f;
    }
    size_t ob = (size_t)b * 3145728 + (size_t)(c0 + 128) * 16384 + (size_t)u * 128 + v;
    #pragma unroll
    for (int cc = 0; cc < 8; ++cc)
        out[ob + (size_t)cc * 16384] = y[cc];
}

extern "C" void kernel_launch(void* const* d_in, const int* in_sizes, int n_in,
                              void* d_out, int out_size, void* d_ws, size_t ws_size,
                              hipStream_t stream) {
    const float* in = (const float*)d_in[0];
    const int* mask = (const int*)d_in[1];
    float* out = (float*)d_out;
    char* ws = (char*)d_ws;
    int* cnt    = (int*)(ws + OFF_CNT);
    int* list   = (int*)(ws + OFF_LIST);
    float* fsub = (float*)(ws + OFF_FSUB);
    float* K5   = (float*)(ws + OFF_K5);
    float* sf   = (float*)(ws + OFF_SF);

    k_front<<<2176, 256, 0, stream>>>(in, mask, cnt, list, fsub, K5, sf, out);
    k_mid2<<<1648, 256, 0, stream>>>(cnt, list, fsub, K5, sf);
    k_tail2<<<dim3(64, 8, 2), 256, 0, stream>>>(in, mask, cnt, list, sf, out);
}